// Round 6
// baseline (97.437 us; speedup 1.0000x reference)
//
#include <hip/hip_runtime.h>
#include <math.h>

#define WIN 11
#define HALF 5
#define SZ 32
#define PST 33          /* padded LDS row stride (row-apron arrays) */
#define PSTA 45         /* stride for column-apron arrays: 42 cols used, odd stride -> <=2-way bank alias (free, m136) */
#define APR 42          /* 32 + 2*5 apron */
#define BB 4
#define NG 16
#define NP 64
#define IH 640
#define IW 640
#define CPIX 1024       /* 32*32 per channel */
#define NPIX 3072       /* 3*32*32 per crop */
#define NCROP 320       /* 64 gt + 256 pred */
#define NPAIR 4096      /* 4*16*64 */
#define NSLOT 512       /* k_pair y-blocks per channel */
#define SSIM_C1 6.5025f
#define SSIM_C2 58.5225f

// exp(-(i-5)^2/4.5)/sum — 11-tap Gaussian, sigma=1.5, compile-time
#define GW_INIT {0.001028379f, 0.007598757f, 0.036000791f, 0.109360748f, \
                 0.213005174f, 0.266011868f, 0.213005174f, 0.109360748f, \
                 0.036000791f, 0.007598757f, 0.001028379f}

// Session lessons encoded:
//  - NO __threadfence (r5: device-scope fence flushes per-XCD L2; +100 µs over 1.5k blocks).
//  - NO contended fp atomicAdd accumulation (r2/r6 vs r3/r7: +16 µs); unique-cell
//    stores + tiny reduce kernel.
//  - NO memset dispatch: ballot compaction writes count/list with plain stores.
//  - r8: do NOT re-gather crops per pair (scattered gathers are the expensive op).
//  - r9: do NOT move per-crop stats (mu/sigma convs) into the per-pair kernel
//    (2.8x conv work + 30KB LDS = +6 µs).
//  - r10: bilinear gather via float2 (bitwise identical, fewer load instrs).
//  - r11 FAILED (+8.6 µs): per-block AGENT-scope ACQ_REL ticket to fold k_final
//    into k_pair. Device-scope ordered atomics flush the issuing XCD's L2.
//    A 1-block k_final dispatch is CHEAPER than any cross-block protocol.
//  - r12/r13 WIN (-3.2 µs): zero-padded LDS aprons -> unconditional conv taps.
//  - r14 WIN (-3.9 µs): crop kernel at 512 threads; 30 waves/CU latency hiding.
//  - r15 NEUTRAL: XCD-locality remap. The 5x source-region reuse was already
//    served by the die-level (cross-XCD-shared) L3; remap only upgraded L3
//    hits to L2 hits, already latency-hidden. XCD swizzles only pay when
//    reuse would otherwise hit HBM. Remap kept (harmless).
//  - r16 (this round): ATTRIBUTION. Two extra k_crop_valid launches into
//    scratch ws; dur delta = 2*(T_crop_warm + launch). Decides whether the
//    ~50 µs gap over the bottom-up model lives in the crop kernel, k_pair,
//    or fixed harness/launch overhead. Real chain unchanged -> absmax 0.

__device__ __forceinline__ bool pair_valid(const float* __restrict__ gt,
                                           const float* __restrict__ pr, int idx) {
    int b = idx >> 10;
    int r = idx & 1023;
    int gi = r >> 6, pi = r & 63;
    const float* g = gt + (b * NG + gi) * 4;
    const float* p = pr + (b * NP + pi) * 4;
    float gx = g[0], gy = g[1], gw = g[2], gh = g[3];
    float px = p[0], py = p[1], pw = p[2], ph = p[3];
    float tlx = fmaxf(gx - gw * 0.5f, px - pw * 0.5f);
    float tly = fmaxf(gy - gh * 0.5f, py - ph * 0.5f);
    float brx = fminf(gx + gw * 0.5f, px + pw * 0.5f);
    float bry = fminf(gy + gh * 0.5f, py + ph * 0.5f);
    float en = ((tlx < brx) && (tly < bry)) ? 1.f : 0.f;
    float ai = (brx - tlx) * (bry - tly) * en;
    float iou = ai / (gw * gh + pw * ph - ai + 1e-16f);
    return (iou > 0.3f && pw > 2.f && ph > 2.f);
}

// ---- fused: crop + mu/sigma (blocks 0..959) | validity compaction (block 960) ----
__global__ __launch_bounds__(512) void k_crop_valid(const float* __restrict__ imgs,
                                                    const float* __restrict__ gt,
                                                    const float* __restrict__ pr,
                                                    float* __restrict__ crops,
                                                    float* __restrict__ mus,
                                                    float* __restrict__ sigs,
                                                    int* __restrict__ list,
                                                    int* __restrict__ count) {
    const int blk = blockIdx.x;
    const int t = threadIdx.x;
    const int wave = t >> 6, lane = t & 63;

    if (blk == 3 * NCROP) {
        // ---- validity -> compact list: 2-pass wave-local ballot, 1 barrier ----
        // 8 waves x 8 iterations x 64 lanes = 4096 pairs
        __shared__ int s_wcnt[8];
        int cnt = 0;
#pragma unroll 1
        for (int i = 0; i < 8; ++i) {
            unsigned long long m = __ballot(pair_valid(gt, pr, wave * 512 + i * 64 + lane));
            cnt += __popcll(m);
        }
        if (lane == 0) s_wcnt[wave] = cnt;
        __syncthreads();
        int base = 0;
#pragma unroll
        for (int w = 0; w < 8; ++w)
            if (w < wave) base += s_wcnt[w];
#pragma unroll 1
        for (int i = 0; i < 8; ++i) {
            int idx = wave * 512 + i * 64 + lane;
            bool v = pair_valid(gt, pr, idx);
            unsigned long long m = __ballot(v);
            if (v) list[base + __popcll(m & ((1ull << lane) - 1ull))] = idx;
            base += __popcll(m);
        }
        if (t == 0) {
            int s = 0;
#pragma unroll
            for (int w = 0; w < 8; ++w) s += s_wcnt[w];
            *count = s;
        }
        return;
    }

    // ---- XCD-locality remap (r15, kept): 960 = 8 xcd * 8 ghi * 15 m ----
    const int xcd = blk & 7;
    const int q = blk >> 3;
    const int ghi = q / 15;          // 0..7
    const int m15 = q - ghi * 15;    // 0..14
    const int g = ghi * 8 + xcd;     // gt-group 0..63
    const int gb = g >> 4, gi = g & 15;   // batch, gt-index
    const int cg = m15 / 3;          // 0 = gt crop, 1..4 = tiled pred crops
    const int c = m15 - cg * 3;      // channel
    int crop;
    if (cg == 0) crop = gb * NG + gi;
    else crop = BB * NG + gb * NP + gi + (cg - 1) * 16;
    const int b = gb;
    const float* box = (cg == 0) ? gt + crop * 4 : pr + (crop - BB * NG) * 4;

    // cr: column apron (x index shifted +5, cols 0..41 valid, 0..4 & 37..41 zero)
    // t1/t2: row apron (y index shifted +5, rows 0..41, 0..4 & 37..41 zero)
    __shared__ float cr[SZ][PSTA];
    __shared__ float t1[APR][PST];
    __shared__ float t2[APR][PST];

    // zero conv aprons once (taps into apron multiply exact 0.0f)
    for (int i = t; i < SZ * 10; i += 512) {
        int r = i / 10, cc = i % 10;
        cr[r][cc < 5 ? cc : cc + 32] = 0.f;
    }
    for (int i = t; i < 10 * PST; i += 512) {
        int r = i / PST, cc = i % PST;
        int rr = (r < 5) ? r : r + 32;
        t1[rr][cc] = 0.f;
        t2[rr][cc] = 0.f;
    }

    // box is wave-uniform -> scalar loads
    float cx = box[0], cy = box[1], bw = box[2], bh = box[3];
    float x0 = fminf(fmaxf(floorf(cx - bw * 0.5f), 0.f), (float)(IW - 1));
    float x1 = fminf(fmaxf(floorf(cx + bw * 0.5f), 0.f), (float)IW);
    float y0 = fminf(fmaxf(floorf(cy - bh * 0.5f), 0.f), (float)(IH - 1));
    float y1 = fminf(fmaxf(floorf(cy + bh * 0.5f), 0.f), (float)IH);
    float wp = fmaxf(x1 - x0, 1.f);
    float hp = fmaxf(y1 - y0, 1.f);
    int xmax = (int)(x0 + wp - 1.f);
    int ymax = (int)(y0 + hp - 1.f);

    const int y = t >> 4;          // thread owns pixels (y, xb..xb+1)
    const int xb = (t & 15) * 2;

    float sy = y0 + fminf(fmaxf(((float)y + 0.5f) * hp * (1.f / 32.f) - 0.5f, 0.f), hp - 1.f);
    float fly = floorf(sy);
    int iy0 = (int)fly;
    float fy = sy - fly;
    int iy1 = min(iy0 + 1, ymax);

    const float* ic = imgs + ((size_t)b * 3 + c) * IH * IW;
    const float* r0 = ic + iy0 * IW;
    const float* r1 = ic + iy1 * IW;
    float vv[2];
#pragma unroll
    for (int j = 0; j < 2; ++j) {
        int x = xb + j;
        float sx = x0 + fminf(fmaxf(((float)x + 0.5f) * wp * (1.f / 32.f) - 0.5f, 0.f), wp - 1.f);
        float flx = floorf(sx);
        int ix0 = (int)flx;
        float fx = sx - flx;
        // float2 gather: ix1==ix0+1 except at the clamp edge; clamped/degenerate
        // lanes have fx==0 or select f.y, so result is bitwise identical to the
        // 4-scalar-load version (0-weight taps multiply a finite value).
        int ixb = max(min(ix0, xmax - 1), 0);
        bool cl = (ix0 > ixb);     // ix0 was at xmax: duplicate high element
        float2 q0 = *(const float2*)(r0 + ixb);
        float2 q1 = *(const float2*)(r1 + ixb);
        float v00 = cl ? q0.y : q0.x;
        float v01 = q0.y;
        float v10 = cl ? q1.y : q1.x;
        float v11 = q1.y;
        vv[j] = v00 * (1.f - fy) * (1.f - fx) + v01 * (1.f - fy) * fx +
                v10 * fy * (1.f - fx) + v11 * fy * fx;
        cr[y][x + 5] = vv[j];
    }
    float* dst = crops + (size_t)crop * NPIX + c * CPIX + t * 2;
    *(float2*)dst = make_float2(vv[0], vv[1]);
    __syncthreads();

    constexpr float GW[WIN] = GW_INIT;
    // horizontal pass on x and x^2 — unconditional taps (apron = 0)
#pragma unroll
    for (int j = 0; j < 2; ++j) {
        int x = xb + j;
        float a1 = 0.f, a2 = 0.f;
#pragma unroll
        for (int k = 0; k < WIN; ++k) {
            float v = cr[y][x + k];        // conceptual col x+k-5, stored +5
            a1 += GW[k] * v;
            a2 += GW[k] * v * v;
        }
        t1[y + 5][x] = a1;
        t2[y + 5][x] = a2;
    }
    __syncthreads();
    // vertical pass — unconditional taps (apron = 0)
    float m[2], s[2];
#pragma unroll
    for (int j = 0; j < 2; ++j) {
        int x = xb + j;
        float a1 = 0.f, a2 = 0.f;
#pragma unroll
        for (int k = 0; k < WIN; ++k) {
            a1 += GW[k] * t1[y + k][x];    // conceptual row y+k-5, stored +5
            a2 += GW[k] * t2[y + k][x];
        }
        m[j] = a1;
        s[j] = a2 - a1 * a1;
    }
    float* mdst = mus + (size_t)crop * NPIX + c * CPIX + t * 2;
    float* sdst = sigs + (size_t)crop * NPIX + c * CPIX + t * 2;
    *(float2*)mdst = make_float2(m[0], m[1]);
    *(float2*)sdst = make_float2(s[0], s[1]);
}

// ---- per-(valid-pair, channel) SSIM + L1; unique-cell stores (r3/r7-measured-fast) ----
__global__ __launch_bounds__(256) void k_pair(const int* __restrict__ list,
                                              const int* __restrict__ count,
                                              const float* __restrict__ crops,
                                              const float* __restrict__ mus,
                                              const float* __restrict__ sigs,
                                              float* __restrict__ pairL1,
                                              float* __restrict__ pairSS) {
    const int c = blockIdx.x;      // 0..2
    const int n = *count;
    const int t = threadIdx.x;
    const int y = t >> 3;
    const int xb = (t & 7) * 4;
    const int wave = t >> 6, lane = t & 63;

    __shared__ float gp[SZ][PSTA];
    __shared__ float tmp[APR][PST];
    __shared__ float rl[4], rs[4];
    constexpr float GW[WIN] = GW_INIT;

    // zero conv aprons once; interior is rewritten each slot iteration
    for (int i = t; i < SZ * 10; i += 256) {
        int r = i / 10, cc = i % 10;
        gp[r][cc < 5 ? cc : cc + 32] = 0.f;
    }
    for (int i = t; i < 10 * PST; i += 256) {
        int r = i / PST, cc = i % PST;
        int rr = (r < 5) ? r : r + 32;
        tmp[rr][cc] = 0.f;
    }

    for (int slot = blockIdx.y; slot < n; slot += NSLOT) {
        const int pair = list[slot];
        const int b = pair >> 10;
        const int r = pair & 1023;
        const int gi = r >> 6, pi = r & 63;
        const size_t goff = (size_t)(b * NG + gi) * NPIX + c * CPIX;
        const size_t poff = (size_t)(BB * NG + b * NP + pi) * NPIX + c * CPIX;

        float4 gv = *(const float4*)(crops + goff + t * 4);
        float4 pv = *(const float4*)(crops + poff + t * 4);
        // hoist mu/sigma loads: in flight across both conv phases
        float4 mg = *(const float4*)(mus + goff + t * 4);
        float4 mp = *(const float4*)(mus + poff + t * 4);
        float4 sg = *(const float4*)(sigs + goff + t * 4);
        float4 sp = *(const float4*)(sigs + poff + t * 4);

        float l1 = fabsf(gv.x - pv.x) + fabsf(gv.y - pv.y) +
                   fabsf(gv.z - pv.z) + fabsf(gv.w - pv.w);
        gp[y][xb + 5] = gv.x * pv.x;
        gp[y][xb + 6] = gv.y * pv.y;
        gp[y][xb + 7] = gv.z * pv.z;
        gp[y][xb + 8] = gv.w * pv.w;
        __syncthreads();

#pragma unroll
        for (int j = 0; j < 4; ++j) {
            int x = xb + j;
            float a = 0.f;
#pragma unroll
            for (int k = 0; k < WIN; ++k) a += GW[k] * gp[y][x + k];
            tmp[y + 5][x] = a;
        }
        __syncthreads();

        float mgv[4] = {mg.x, mg.y, mg.z, mg.w};
        float mpv[4] = {mp.x, mp.y, mp.z, mp.w};
        float sgv[4] = {sg.x, sg.y, sg.z, sg.w};
        float spv[4] = {sp.x, sp.y, sp.z, sp.w};
        float ss = 0.f;
#pragma unroll
        for (int j = 0; j < 4; ++j) {
            int x = xb + j;
            float a = 0.f;
#pragma unroll
            for (int k = 0; k < WIN; ++k) a += GW[k] * tmp[y + k][x];
            float m1 = mgv[j], m2 = mpv[j];
            float sgp = a - m1 * m2;
            float num = (2.f * m1 * m2 + SSIM_C1) * (2.f * sgp + SSIM_C2);
            float den = (m1 * m1 + m2 * m2 + SSIM_C1) * (sgv[j] + spv[j] + SSIM_C2);
            ss += num / den;
        }

        // block reduction: 64-lane shuffle, then LDS across 4 waves
#pragma unroll
        for (int off = 32; off > 0; off >>= 1) {
            l1 += __shfl_down(l1, off);
            ss += __shfl_down(ss, off);
        }
        if (lane == 0) { rl[wave] = l1; rs[wave] = ss; }
        __syncthreads();
        if (t == 0) {
            pairL1[slot * 3 + c] = rl[0] + rl[1] + rl[2] + rl[3];
            pairSS[slot * 3 + c] = rs[0] + rs[1] + rs[2] + rs[3];
        }
    }
}

// ---- finalize: deterministic reduction over compact results ----
__global__ __launch_bounds__(256) void k_final(const int* __restrict__ count,
                                               const float* __restrict__ pairL1,
                                               const float* __restrict__ pairSS,
                                               float* __restrict__ out) {
    const int n3 = (*count) * 3;
    const int t = threadIdx.x;
    float L = 0.f, S = 0.f;
    for (int i = t; i < n3; i += 256) {
        L += pairL1[i];
        S += pairSS[i];
    }
    __shared__ float rl[4], rs[4];
#pragma unroll
    for (int off = 32; off > 0; off >>= 1) {
        L += __shfl_down(L, off);
        S += __shfl_down(S, off);
    }
    const int wave = t >> 6, lane = t & 63;
    if (lane == 0) { rl[wave] = L; rs[wave] = S; }
    __syncthreads();
    if (t == 0) {
        float cnt = (float)(*count);
        float Lt = (rl[0] + rl[1] + rl[2] + rl[3]) * (1.0f / (255.0f * (float)NPIX));
        float St = (rs[0] + rs[1] + rs[2] + rs[3]) * (1.0f / (float)NPIX);
        float m = fmaxf(cnt, 1.f);
        float loss = Lt / m + 1.f - St / m;
        out[0] = (cnt > 0.f) ? loss : 0.f;
    }
}

extern "C" void kernel_launch(void* const* d_in, const int* in_sizes, int n_in,
                              void* d_out, int out_size, void* d_ws, size_t ws_size,
                              hipStream_t stream) {
    const float* imgs = (const float*)d_in[0];  // (4,3,640,640)
    const float* gt = (const float*)d_in[1];    // (4,16,4)
    const float* pr = (const float*)d_in[2];    // (4,64,4)

    float* ws = (float*)d_ws;
    float* crops = ws;                                   // 320*3072
    float* mus = crops + (size_t)NCROP * NPIX;
    float* sigs = mus + (size_t)NCROP * NPIX;
    float* pairL1 = sigs + (size_t)NCROP * NPIX;         // 4096*3
    float* pairSS = pairL1 + (size_t)NPAIR * 3;          // 4096*3
    int* list = (int*)(pairSS + (size_t)NPAIR * 3);      // 4096
    int* count = list + NPAIR;                           // 1

    // r16 attribution scratch: a second, independent output set at +8M floats
    // (32 MB into the 256 MB ws; real set uses < 12 MB). Writes here can never
    // affect d_out.
    float* ws2 = ws + (size_t)8 * 1024 * 1024;
    float* crops2 = ws2;
    float* mus2 = crops2 + (size_t)NCROP * NPIX;
    float* sigs2 = mus2 + (size_t)NCROP * NPIX;
    int* list2 = (int*)(sigs2 + (size_t)NCROP * NPIX);
    int* count2 = list2 + NPAIR;

    // real chain (unchanged)
    k_crop_valid<<<3 * NCROP + 1, 512, 0, stream>>>(imgs, gt, pr, crops, mus, sigs,
                                                    list, count);
    k_pair<<<dim3(3, NSLOT), 256, 0, stream>>>(list, count, crops, mus, sigs,
                                               pairL1, pairSS);
    k_final<<<1, 256, 0, stream>>>(count, pairL1, pairSS, (float*)d_out);

    // r16 measurement appendix: two duplicate crop launches into scratch.
    // dur_us delta vs r15 (81.4) = 2*(T_crop_warm + launch). Interpretation
    // pre-committed in the session journal; these will be removed next round.
    k_crop_valid<<<3 * NCROP + 1, 512, 0, stream>>>(imgs, gt, pr, crops2, mus2, sigs2,
                                                    list2, count2);
    k_crop_valid<<<3 * NCROP + 1, 512, 0, stream>>>(imgs, gt, pr, crops2, mus2, sigs2,
                                                    list2, count2);
}

// Round 7
// 83.774 us; speedup vs baseline: 1.1631x; 1.1631x over previous
//
#include <hip/hip_runtime.h>
#include <math.h>

#define WIN 11
#define HALF 5
#define SZ 32
#define PST 33          /* padded LDS row stride (row-apron arrays) */
#define PSTA 45         /* stride for column-apron arrays: 42 cols used, odd stride -> <=2-way bank alias (free, m136) */
#define APR 42          /* 32 + 2*5 apron */
#define BB 4
#define NG 16
#define NP 64
#define IH 640
#define IW 640
#define CPIX 1024       /* 32*32 per channel */
#define NPIX 3072       /* 3*32*32 per crop */
#define NCROP 320       /* 64 gt + 256 pred */
#define NPAIR 4096      /* 4*16*64 */
#define NSLOT 512       /* k_pair y-blocks per channel */
#define NWARM 96        /* L3-warmer blocks at the front of the crop dispatch */
#define SSIM_C1 6.5025f
#define SSIM_C2 58.5225f

// exp(-(i-5)^2/4.5)/sum — 11-tap Gaussian, sigma=1.5, compile-time
#define GW_INIT {0.001028379f, 0.007598757f, 0.036000791f, 0.109360748f, \
                 0.213005174f, 0.266011868f, 0.213005174f, 0.109360748f, \
                 0.036000791f, 0.007598757f, 0.001028379f}

// Session lessons encoded:
//  - NO __threadfence (r5) / NO per-block device-scope ordered atomics (r11:
//    +8.6 µs): both flush the issuing XCD's L2. A tiny extra dispatch is
//    always cheaper than a cross-block completion protocol.
//  - NO contended fp atomicAdd (r2/r6); unique-cell stores + tiny reduce.
//  - r8: do NOT re-gather crops per pair. r9: keep per-crop stats at crop level.
//  - r10: bilinear gather via float2 (bitwise identical).
//  - r12/r13 WIN (-3.2): zero-padded LDS aprons -> unconditional conv taps.
//  - r14 WIN (-3.9): crop kernel at 512 threads (30 waves/CU latency hiding).
//  - r15 NEUTRAL: XCD remap — the 5x source reuse was already L3-absorbed
//    (L3 is die-level, cross-XCD). XCD swizzles only pay vs HBM, not vs L3.
//  - r16 ATTRIBUTION: T_crop(warm)+launch = 8.0 µs (16.0/2). Kernels total
//    ~15-20 µs; the harness's 256 MB poison fill (44 µs) + ~3 dispatch
//    boundaries are INSIDE the timed window. Controllable budget ~37 µs.
//  - r17 (this round): (a) 96 in-dispatch L3-warmer blocks stream imgs
//    (19.6 MB) coalesced into the die-level L3 ahead of the scattered crop
//    gathers — no extra dispatch boundary; (b) gather loads issued BEFORE
//    the LDS apron zeroing so the ~40 LDS stores hide miss latency.

__device__ __forceinline__ bool pair_valid(const float* __restrict__ gt,
                                           const float* __restrict__ pr, int idx) {
    int b = idx >> 10;
    int r = idx & 1023;
    int gi = r >> 6, pi = r & 63;
    const float* g = gt + (b * NG + gi) * 4;
    const float* p = pr + (b * NP + pi) * 4;
    float gx = g[0], gy = g[1], gw = g[2], gh = g[3];
    float px = p[0], py = p[1], pw = p[2], ph = p[3];
    float tlx = fmaxf(gx - gw * 0.5f, px - pw * 0.5f);
    float tly = fmaxf(gy - gh * 0.5f, py - ph * 0.5f);
    float brx = fminf(gx + gw * 0.5f, px + pw * 0.5f);
    float bry = fminf(gy + gh * 0.5f, py + ph * 0.5f);
    float en = ((tlx < brx) && (tly < bry)) ? 1.f : 0.f;
    float ai = (brx - tlx) * (bry - tly) * en;
    float iou = ai / (gw * gh + pw * ph - ai + 1e-16f);
    return (iou > 0.3f && pw > 2.f && ph > 2.f);
}

// ---- fused: L3 warmers (blocks 0..95) | crop + mu/sigma (96..1055) |
//      validity compaction (block 1056) ----
__global__ __launch_bounds__(512) void k_crop_valid(const float* __restrict__ imgs,
                                                    const float* __restrict__ gt,
                                                    const float* __restrict__ pr,
                                                    float* __restrict__ crops,
                                                    float* __restrict__ mus,
                                                    float* __restrict__ sigs,
                                                    int* __restrict__ list,
                                                    int* __restrict__ count,
                                                    float* __restrict__ warmsink) {
    const int blk = blockIdx.x;
    const int t = threadIdx.x;
    const int wave = t >> 6, lane = t & 63;

    if (blk < NWARM) {
        // ---- L3 warmer: stream imgs coalesced into the die-level L3 while
        // the crop blocks start. Keep-alive sum stored to scratch (never read
        // by the real chain). Perf-only: no ordering or correctness reliance.
        const float4* p4 = (const float4*)imgs;
        const int total = BB * 3 * IH * IW / 4;   // 1,228,800 float4s
        float acc = 0.f;
        for (int i = blk * 512 + t; i < total; i += NWARM * 512) {
            float4 v = p4[i];
            acc += v.x + v.y + v.z + v.w;
        }
        warmsink[blk * 512 + t] = acc;
        return;
    }

    if (blk == NWARM + 3 * NCROP) {
        // ---- validity -> compact list: 2-pass wave-local ballot, 1 barrier ----
        // 8 waves x 8 iterations x 64 lanes = 4096 pairs
        __shared__ int s_wcnt[8];
        int cnt = 0;
#pragma unroll 1
        for (int i = 0; i < 8; ++i) {
            unsigned long long m = __ballot(pair_valid(gt, pr, wave * 512 + i * 64 + lane));
            cnt += __popcll(m);
        }
        if (lane == 0) s_wcnt[wave] = cnt;
        __syncthreads();
        int base = 0;
#pragma unroll
        for (int w = 0; w < 8; ++w)
            if (w < wave) base += s_wcnt[w];
#pragma unroll 1
        for (int i = 0; i < 8; ++i) {
            int idx = wave * 512 + i * 64 + lane;
            bool v = pair_valid(gt, pr, idx);
            unsigned long long m = __ballot(v);
            if (v) list[base + __popcll(m & ((1ull << lane) - 1ull))] = idx;
            base += __popcll(m);
        }
        if (t == 0) {
            int s = 0;
#pragma unroll
            for (int w = 0; w < 8; ++w) s += s_wcnt[w];
            *count = s;
        }
        return;
    }

    // ---- XCD-locality remap (r15, kept): 960 = 8 xcd * 8 ghi * 15 m ----
    const int blk2 = blk - NWARM;
    const int xcd = blk2 & 7;
    const int q = blk2 >> 3;
    const int ghi = q / 15;          // 0..7
    const int m15 = q - ghi * 15;    // 0..14
    const int g = ghi * 8 + xcd;     // gt-group 0..63
    const int gb = g >> 4, gi = g & 15;   // batch, gt-index
    const int cg = m15 / 3;          // 0 = gt crop, 1..4 = tiled pred crops
    const int c = m15 - cg * 3;      // channel
    int crop;
    if (cg == 0) crop = gb * NG + gi;
    else crop = BB * NG + gb * NP + gi + (cg - 1) * 16;
    const int b = gb;
    const float* box = (cg == 0) ? gt + crop * 4 : pr + (crop - BB * NG) * 4;

    // cr: column apron (x index shifted +5, cols 0..41 valid, 0..4 & 37..41 zero)
    // t1/t2: row apron (y index shifted +5, rows 0..41, 0..4 & 37..41 zero)
    __shared__ float cr[SZ][PSTA];
    __shared__ float t1[APR][PST];
    __shared__ float t2[APR][PST];

    // box is wave-uniform -> scalar loads
    float cx = box[0], cy = box[1], bw = box[2], bh = box[3];
    float x0 = fminf(fmaxf(floorf(cx - bw * 0.5f), 0.f), (float)(IW - 1));
    float x1 = fminf(fmaxf(floorf(cx + bw * 0.5f), 0.f), (float)IW);
    float y0 = fminf(fmaxf(floorf(cy - bh * 0.5f), 0.f), (float)(IH - 1));
    float y1 = fminf(fmaxf(floorf(cy + bh * 0.5f), 0.f), (float)IH);
    float wp = fmaxf(x1 - x0, 1.f);
    float hp = fmaxf(y1 - y0, 1.f);
    int xmax = (int)(x0 + wp - 1.f);
    int ymax = (int)(y0 + hp - 1.f);

    const int y = t >> 4;          // thread owns pixels (y, xb..xb+1)
    const int xb = (t & 15) * 2;

    float sy = y0 + fminf(fmaxf(((float)y + 0.5f) * hp * (1.f / 32.f) - 0.5f, 0.f), hp - 1.f);
    float fly = floorf(sy);
    int iy0 = (int)fly;
    float fy = sy - fly;
    int iy1 = min(iy0 + 1, ymax);

    const float* ic = imgs + ((size_t)b * 3 + c) * IH * IW;
    const float* r0 = ic + iy0 * IW;
    const float* r1 = ic + iy1 * IW;

    // ---- issue all 4 gathers FIRST (r17b): the LDS apron zeroing below
    // executes while these misses are in flight.
    float fxv[2];
    bool clv[2];
    float2 q0v[2], q1v[2];
#pragma unroll
    for (int j = 0; j < 2; ++j) {
        int x = xb + j;
        float sx = x0 + fminf(fmaxf(((float)x + 0.5f) * wp * (1.f / 32.f) - 0.5f, 0.f), wp - 1.f);
        float flx = floorf(sx);
        int ix0 = (int)flx;
        fxv[j] = sx - flx;
        int ixb = max(min(ix0, xmax - 1), 0);
        clv[j] = (ix0 > ixb);     // ix0 was at xmax: duplicate high element
        q0v[j] = *(const float2*)(r0 + ixb);
        q1v[j] = *(const float2*)(r1 + ixb);
    }

    // zero conv aprons (taps into apron multiply exact 0.0f) — overlaps loads
    for (int i = t; i < SZ * 10; i += 512) {
        int r = i / 10, cc = i % 10;
        cr[r][cc < 5 ? cc : cc + 32] = 0.f;
    }
    for (int i = t; i < 10 * PST; i += 512) {
        int r = i / PST, cc = i % PST;
        int rr = (r < 5) ? r : r + 32;
        t1[rr][cc] = 0.f;
        t2[rr][cc] = 0.f;
    }

    float vv[2];
#pragma unroll
    for (int j = 0; j < 2; ++j) {
        int x = xb + j;
        float fx = fxv[j];
        // float2 gather semantics: clamped/degenerate lanes have fx==0 or
        // select .y, so result is bitwise identical to 4 scalar loads.
        float v00 = clv[j] ? q0v[j].y : q0v[j].x;
        float v01 = q0v[j].y;
        float v10 = clv[j] ? q1v[j].y : q1v[j].x;
        float v11 = q1v[j].y;
        vv[j] = v00 * (1.f - fy) * (1.f - fx) + v01 * (1.f - fy) * fx +
                v10 * fy * (1.f - fx) + v11 * fy * fx;
        cr[y][x + 5] = vv[j];
    }
    float* dst = crops + (size_t)crop * NPIX + c * CPIX + t * 2;
    *(float2*)dst = make_float2(vv[0], vv[1]);
    __syncthreads();

    constexpr float GW[WIN] = GW_INIT;
    // horizontal pass on x and x^2 — unconditional taps (apron = 0)
#pragma unroll
    for (int j = 0; j < 2; ++j) {
        int x = xb + j;
        float a1 = 0.f, a2 = 0.f;
#pragma unroll
        for (int k = 0; k < WIN; ++k) {
            float v = cr[y][x + k];        // conceptual col x+k-5, stored +5
            a1 += GW[k] * v;
            a2 += GW[k] * v * v;
        }
        t1[y + 5][x] = a1;
        t2[y + 5][x] = a2;
    }
    __syncthreads();
    // vertical pass — unconditional taps (apron = 0)
    float m[2], s[2];
#pragma unroll
    for (int j = 0; j < 2; ++j) {
        int x = xb + j;
        float a1 = 0.f, a2 = 0.f;
#pragma unroll
        for (int k = 0; k < WIN; ++k) {
            a1 += GW[k] * t1[y + k][x];    // conceptual row y+k-5, stored +5
            a2 += GW[k] * t2[y + k][x];
        }
        m[j] = a1;
        s[j] = a2 - a1 * a1;
    }
    float* mdst = mus + (size_t)crop * NPIX + c * CPIX + t * 2;
    float* sdst = sigs + (size_t)crop * NPIX + c * CPIX + t * 2;
    *(float2*)mdst = make_float2(m[0], m[1]);
    *(float2*)sdst = make_float2(s[0], s[1]);
}

// ---- per-(valid-pair, channel) SSIM + L1; unique-cell stores (r3/r7-measured-fast) ----
__global__ __launch_bounds__(256) void k_pair(const int* __restrict__ list,
                                              const int* __restrict__ count,
                                              const float* __restrict__ crops,
                                              const float* __restrict__ mus,
                                              const float* __restrict__ sigs,
                                              float* __restrict__ pairL1,
                                              float* __restrict__ pairSS) {
    const int c = blockIdx.x;      // 0..2
    const int n = *count;
    const int t = threadIdx.x;
    const int y = t >> 3;
    const int xb = (t & 7) * 4;
    const int wave = t >> 6, lane = t & 63;

    __shared__ float gp[SZ][PSTA];
    __shared__ float tmp[APR][PST];
    __shared__ float rl[4], rs[4];
    constexpr float GW[WIN] = GW_INIT;

    // zero conv aprons once; interior is rewritten each slot iteration
    for (int i = t; i < SZ * 10; i += 256) {
        int r = i / 10, cc = i % 10;
        gp[r][cc < 5 ? cc : cc + 32] = 0.f;
    }
    for (int i = t; i < 10 * PST; i += 256) {
        int r = i / PST, cc = i % PST;
        int rr = (r < 5) ? r : r + 32;
        tmp[rr][cc] = 0.f;
    }

    for (int slot = blockIdx.y; slot < n; slot += NSLOT) {
        const int pair = list[slot];
        const int b = pair >> 10;
        const int r = pair & 1023;
        const int gi = r >> 6, pi = r & 63;
        const size_t goff = (size_t)(b * NG + gi) * NPIX + c * CPIX;
        const size_t poff = (size_t)(BB * NG + b * NP + pi) * NPIX + c * CPIX;

        float4 gv = *(const float4*)(crops + goff + t * 4);
        float4 pv = *(const float4*)(crops + poff + t * 4);
        // hoist mu/sigma loads: in flight across both conv phases
        float4 mg = *(const float4*)(mus + goff + t * 4);
        float4 mp = *(const float4*)(mus + poff + t * 4);
        float4 sg = *(const float4*)(sigs + goff + t * 4);
        float4 sp = *(const float4*)(sigs + poff + t * 4);

        float l1 = fabsf(gv.x - pv.x) + fabsf(gv.y - pv.y) +
                   fabsf(gv.z - pv.z) + fabsf(gv.w - pv.w);
        gp[y][xb + 5] = gv.x * pv.x;
        gp[y][xb + 6] = gv.y * pv.y;
        gp[y][xb + 7] = gv.z * pv.z;
        gp[y][xb + 8] = gv.w * pv.w;
        __syncthreads();

#pragma unroll
        for (int j = 0; j < 4; ++j) {
            int x = xb + j;
            float a = 0.f;
#pragma unroll
            for (int k = 0; k < WIN; ++k) a += GW[k] * gp[y][x + k];
            tmp[y + 5][x] = a;
        }
        __syncthreads();

        float mgv[4] = {mg.x, mg.y, mg.z, mg.w};
        float mpv[4] = {mp.x, mp.y, mp.z, mp.w};
        float sgv[4] = {sg.x, sg.y, sg.z, sg.w};
        float spv[4] = {sp.x, sp.y, sp.z, sp.w};
        float ss = 0.f;
#pragma unroll
        for (int j = 0; j < 4; ++j) {
            int x = xb + j;
            float a = 0.f;
#pragma unroll
            for (int k = 0; k < WIN; ++k) a += GW[k] * tmp[y + k][x];
            float m1 = mgv[j], m2 = mpv[j];
            float sgp = a - m1 * m2;
            float num = (2.f * m1 * m2 + SSIM_C1) * (2.f * sgp + SSIM_C2);
            float den = (m1 * m1 + m2 * m2 + SSIM_C1) * (sgv[j] + spv[j] + SSIM_C2);
            ss += num / den;
        }

        // block reduction: 64-lane shuffle, then LDS across 4 waves
#pragma unroll
        for (int off = 32; off > 0; off >>= 1) {
            l1 += __shfl_down(l1, off);
            ss += __shfl_down(ss, off);
        }
        if (lane == 0) { rl[wave] = l1; rs[wave] = ss; }
        __syncthreads();
        if (t == 0) {
            pairL1[slot * 3 + c] = rl[0] + rl[1] + rl[2] + rl[3];
            pairSS[slot * 3 + c] = rs[0] + rs[1] + rs[2] + rs[3];
        }
    }
}

// ---- finalize: deterministic reduction over compact results ----
__global__ __launch_bounds__(256) void k_final(const int* __restrict__ count,
                                               const float* __restrict__ pairL1,
                                               const float* __restrict__ pairSS,
                                               float* __restrict__ out) {
    const int n3 = (*count) * 3;
    const int t = threadIdx.x;
    float L = 0.f, S = 0.f;
    for (int i = t; i < n3; i += 256) {
        L += pairL1[i];
        S += pairSS[i];
    }
    __shared__ float rl[4], rs[4];
#pragma unroll
    for (int off = 32; off > 0; off >>= 1) {
        L += __shfl_down(L, off);
        S += __shfl_down(S, off);
    }
    const int wave = t >> 6, lane = t & 63;
    if (lane == 0) { rl[wave] = L; rs[wave] = S; }
    __syncthreads();
    if (t == 0) {
        float cnt = (float)(*count);
        float Lt = (rl[0] + rl[1] + rl[2] + rl[3]) * (1.0f / (255.0f * (float)NPIX));
        float St = (rs[0] + rs[1] + rs[2] + rs[3]) * (1.0f / (float)NPIX);
        float m = fmaxf(cnt, 1.f);
        float loss = Lt / m + 1.f - St / m;
        out[0] = (cnt > 0.f) ? loss : 0.f;
    }
}

extern "C" void kernel_launch(void* const* d_in, const int* in_sizes, int n_in,
                              void* d_out, int out_size, void* d_ws, size_t ws_size,
                              hipStream_t stream) {
    const float* imgs = (const float*)d_in[0];  // (4,3,640,640)
    const float* gt = (const float*)d_in[1];    // (4,16,4)
    const float* pr = (const float*)d_in[2];    // (4,64,4)

    float* ws = (float*)d_ws;
    float* crops = ws;                                   // 320*3072
    float* mus = crops + (size_t)NCROP * NPIX;
    float* sigs = mus + (size_t)NCROP * NPIX;
    float* pairL1 = sigs + (size_t)NCROP * NPIX;         // 4096*3
    float* pairSS = pairL1 + (size_t)NPAIR * 3;          // 4096*3
    int* list = (int*)(pairSS + (size_t)NPAIR * 3);      // 4096
    int* count = list + NPAIR;                           // 1
    float* warmsink = ws + (size_t)8 * 1024 * 1024;      // scratch, never read

    k_crop_valid<<<NWARM + 3 * NCROP + 1, 512, 0, stream>>>(imgs, gt, pr, crops,
                                                            mus, sigs, list, count,
                                                            warmsink);
    k_pair<<<dim3(3, NSLOT), 256, 0, stream>>>(list, count, crops, mus, sigs,
                                               pairL1, pairSS);
    k_final<<<1, 256, 0, stream>>>(count, pairL1, pairSS, (float*)d_out);
}

// Round 8
// 82.935 us; speedup vs baseline: 1.1749x; 1.0101x over previous
//
#include <hip/hip_runtime.h>
#include <math.h>

#define WIN 11
#define HALF 5
#define SZ 32
#define PST 33          /* padded LDS row stride (row-apron arrays) */
#define PSTA 45         /* stride for column-apron arrays: 42 cols used, odd stride -> <=2-way bank alias (free, m136) */
#define APR 42          /* 32 + 2*5 apron */
#define BB 4
#define NG 16
#define NP 64
#define IH 640
#define IW 640
#define CPIX 1024       /* 32*32 per channel */
#define NPIX 3072       /* 3*32*32 per crop */
#define NCROP 320       /* 64 gt + 256 pred */
#define NPAIR 4096      /* 4*16*64 */
#define NSLOT 512       /* k_pair y-blocks per channel */
#define SSIM_C1 6.5025f
#define SSIM_C2 58.5225f

// exp(-(i-5)^2/4.5)/sum — 11-tap Gaussian, sigma=1.5, compile-time
#define GW_INIT {0.001028379f, 0.007598757f, 0.036000791f, 0.109360748f, \
                 0.213005174f, 0.266011868f, 0.213005174f, 0.109360748f, \
                 0.036000791f, 0.007598757f, 0.001028379f}

// Session lessons encoded:
//  - NO __threadfence (r5) / NO per-block device-scope ordered atomics (r11:
//    +8.6 µs): both flush the issuing XCD's L2. A tiny extra dispatch is
//    always cheaper than a cross-block completion protocol.
//  - NO contended fp atomicAdd (r2/r6); unique-cell stores + tiny reduce.
//  - r8: do NOT re-gather crops per pair. r9: keep per-crop stats at crop level.
//  - r10: bilinear gather via float2 (bitwise identical).
//  - r12/r13 WIN (-3.2): zero-padded LDS aprons -> unconditional conv taps.
//  - r14 WIN (-3.9): crop kernel at 512 threads (30 waves/CU latency hiding).
//  - r15 NEUTRAL: XCD remap — 5x source reuse already absorbed by die-level
//    L3. Cache-locality swizzles only pay vs HBM, not vs L3. Kept (harmless).
//  - r16 ATTRIBUTION: T_crop(warm)+launch = 8.0 µs. Kernel total ~15-20 µs;
//    the harness 256 MB poison fill (44 µs) + dispatch boundaries are INSIDE
//    the timed window. Controllable budget ~20 µs of 81.
//  - r17 FAILED (+2.4): in-dispatch L3 warmers. Warmer blocks occupy the
//    dispatch front (~5 µs of streaming) to save latency that r14's TLP
//    already hides. No cache-side win left in the crop kernel.
//  - r18 (this round): revert warmers to the r15 grid; keep only the r17b
//    gather-before-apron-zero reorder (pure instruction scheduling, free).
//    If this lands at 81.4±1 -> structural floor confirmed -> ROOFLINE.

__device__ __forceinline__ bool pair_valid(const float* __restrict__ gt,
                                           const float* __restrict__ pr, int idx) {
    int b = idx >> 10;
    int r = idx & 1023;
    int gi = r >> 6, pi = r & 63;
    const float* g = gt + (b * NG + gi) * 4;
    const float* p = pr + (b * NP + pi) * 4;
    float gx = g[0], gy = g[1], gw = g[2], gh = g[3];
    float px = p[0], py = p[1], pw = p[2], ph = p[3];
    float tlx = fmaxf(gx - gw * 0.5f, px - pw * 0.5f);
    float tly = fmaxf(gy - gh * 0.5f, py - ph * 0.5f);
    float brx = fminf(gx + gw * 0.5f, px + pw * 0.5f);
    float bry = fminf(gy + gh * 0.5f, py + ph * 0.5f);
    float en = ((tlx < brx) && (tly < bry)) ? 1.f : 0.f;
    float ai = (brx - tlx) * (bry - tly) * en;
    float iou = ai / (gw * gh + pw * ph - ai + 1e-16f);
    return (iou > 0.3f && pw > 2.f && ph > 2.f);
}

// ---- fused: crop + mu/sigma (blocks 0..959) | validity compaction (block 960) ----
__global__ __launch_bounds__(512) void k_crop_valid(const float* __restrict__ imgs,
                                                    const float* __restrict__ gt,
                                                    const float* __restrict__ pr,
                                                    float* __restrict__ crops,
                                                    float* __restrict__ mus,
                                                    float* __restrict__ sigs,
                                                    int* __restrict__ list,
                                                    int* __restrict__ count) {
    const int blk = blockIdx.x;
    const int t = threadIdx.x;
    const int wave = t >> 6, lane = t & 63;

    if (blk == 3 * NCROP) {
        // ---- validity -> compact list: 2-pass wave-local ballot, 1 barrier ----
        // 8 waves x 8 iterations x 64 lanes = 4096 pairs
        __shared__ int s_wcnt[8];
        int cnt = 0;
#pragma unroll 1
        for (int i = 0; i < 8; ++i) {
            unsigned long long m = __ballot(pair_valid(gt, pr, wave * 512 + i * 64 + lane));
            cnt += __popcll(m);
        }
        if (lane == 0) s_wcnt[wave] = cnt;
        __syncthreads();
        int base = 0;
#pragma unroll
        for (int w = 0; w < 8; ++w)
            if (w < wave) base += s_wcnt[w];
#pragma unroll 1
        for (int i = 0; i < 8; ++i) {
            int idx = wave * 512 + i * 64 + lane;
            bool v = pair_valid(gt, pr, idx);
            unsigned long long m = __ballot(v);
            if (v) list[base + __popcll(m & ((1ull << lane) - 1ull))] = idx;
            base += __popcll(m);
        }
        if (t == 0) {
            int s = 0;
#pragma unroll
            for (int w = 0; w < 8; ++w) s += s_wcnt[w];
            *count = s;
        }
        return;
    }

    // ---- XCD-locality remap (r15, kept): 960 = 8 xcd * 8 ghi * 15 m ----
    const int xcd = blk & 7;
    const int q = blk >> 3;
    const int ghi = q / 15;          // 0..7
    const int m15 = q - ghi * 15;    // 0..14
    const int g = ghi * 8 + xcd;     // gt-group 0..63
    const int gb = g >> 4, gi = g & 15;   // batch, gt-index
    const int cg = m15 / 3;          // 0 = gt crop, 1..4 = tiled pred crops
    const int c = m15 - cg * 3;      // channel
    int crop;
    if (cg == 0) crop = gb * NG + gi;
    else crop = BB * NG + gb * NP + gi + (cg - 1) * 16;
    const int b = gb;
    const float* box = (cg == 0) ? gt + crop * 4 : pr + (crop - BB * NG) * 4;

    // cr: column apron (x index shifted +5, cols 0..41 valid, 0..4 & 37..41 zero)
    // t1/t2: row apron (y index shifted +5, rows 0..41, 0..4 & 37..41 zero)
    __shared__ float cr[SZ][PSTA];
    __shared__ float t1[APR][PST];
    __shared__ float t2[APR][PST];

    // box is wave-uniform -> scalar loads
    float cx = box[0], cy = box[1], bw = box[2], bh = box[3];
    float x0 = fminf(fmaxf(floorf(cx - bw * 0.5f), 0.f), (float)(IW - 1));
    float x1 = fminf(fmaxf(floorf(cx + bw * 0.5f), 0.f), (float)IW);
    float y0 = fminf(fmaxf(floorf(cy - bh * 0.5f), 0.f), (float)(IH - 1));
    float y1 = fminf(fmaxf(floorf(cy + bh * 0.5f), 0.f), (float)IH);
    float wp = fmaxf(x1 - x0, 1.f);
    float hp = fmaxf(y1 - y0, 1.f);
    int xmax = (int)(x0 + wp - 1.f);
    int ymax = (int)(y0 + hp - 1.f);

    const int y = t >> 4;          // thread owns pixels (y, xb..xb+1)
    const int xb = (t & 15) * 2;

    float sy = y0 + fminf(fmaxf(((float)y + 0.5f) * hp * (1.f / 32.f) - 0.5f, 0.f), hp - 1.f);
    float fly = floorf(sy);
    int iy0 = (int)fly;
    float fy = sy - fly;
    int iy1 = min(iy0 + 1, ymax);

    const float* ic = imgs + ((size_t)b * 3 + c) * IH * IW;
    const float* r0 = ic + iy0 * IW;
    const float* r1 = ic + iy1 * IW;

    // ---- issue all 4 gathers FIRST (r17b): the LDS apron zeroing below
    // executes while these misses are in flight.
    float fxv[2];
    bool clv[2];
    float2 q0v[2], q1v[2];
#pragma unroll
    for (int j = 0; j < 2; ++j) {
        int x = xb + j;
        float sx = x0 + fminf(fmaxf(((float)x + 0.5f) * wp * (1.f / 32.f) - 0.5f, 0.f), wp - 1.f);
        float flx = floorf(sx);
        int ix0 = (int)flx;
        fxv[j] = sx - flx;
        int ixb = max(min(ix0, xmax - 1), 0);
        clv[j] = (ix0 > ixb);     // ix0 was at xmax: duplicate high element
        q0v[j] = *(const float2*)(r0 + ixb);
        q1v[j] = *(const float2*)(r1 + ixb);
    }

    // zero conv aprons (taps into apron multiply exact 0.0f) — overlaps loads
    for (int i = t; i < SZ * 10; i += 512) {
        int r = i / 10, cc = i % 10;
        cr[r][cc < 5 ? cc : cc + 32] = 0.f;
    }
    for (int i = t; i < 10 * PST; i += 512) {
        int r = i / PST, cc = i % PST;
        int rr = (r < 5) ? r : r + 32;
        t1[rr][cc] = 0.f;
        t2[rr][cc] = 0.f;
    }

    float vv[2];
#pragma unroll
    for (int j = 0; j < 2; ++j) {
        int x = xb + j;
        float fx = fxv[j];
        // float2 gather semantics: clamped/degenerate lanes have fx==0 or
        // select .y, so result is bitwise identical to 4 scalar loads.
        float v00 = clv[j] ? q0v[j].y : q0v[j].x;
        float v01 = q0v[j].y;
        float v10 = clv[j] ? q1v[j].y : q1v[j].x;
        float v11 = q1v[j].y;
        vv[j] = v00 * (1.f - fy) * (1.f - fx) + v01 * (1.f - fy) * fx +
                v10 * fy * (1.f - fx) + v11 * fy * fx;
        cr[y][x + 5] = vv[j];
    }
    float* dst = crops + (size_t)crop * NPIX + c * CPIX + t * 2;
    *(float2*)dst = make_float2(vv[0], vv[1]);
    __syncthreads();

    constexpr float GW[WIN] = GW_INIT;
    // horizontal pass on x and x^2 — unconditional taps (apron = 0)
#pragma unroll
    for (int j = 0; j < 2; ++j) {
        int x = xb + j;
        float a1 = 0.f, a2 = 0.f;
#pragma unroll
        for (int k = 0; k < WIN; ++k) {
            float v = cr[y][x + k];        // conceptual col x+k-5, stored +5
            a1 += GW[k] * v;
            a2 += GW[k] * v * v;
        }
        t1[y + 5][x] = a1;
        t2[y + 5][x] = a2;
    }
    __syncthreads();
    // vertical pass — unconditional taps (apron = 0)
    float m[2], s[2];
#pragma unroll
    for (int j = 0; j < 2; ++j) {
        int x = xb + j;
        float a1 = 0.f, a2 = 0.f;
#pragma unroll
        for (int k = 0; k < WIN; ++k) {
            a1 += GW[k] * t1[y + k][x];    // conceptual row y+k-5, stored +5
            a2 += GW[k] * t2[y + k][x];
        }
        m[j] = a1;
        s[j] = a2 - a1 * a1;
    }
    float* mdst = mus + (size_t)crop * NPIX + c * CPIX + t * 2;
    float* sdst = sigs + (size_t)crop * NPIX + c * CPIX + t * 2;
    *(float2*)mdst = make_float2(m[0], m[1]);
    *(float2*)sdst = make_float2(s[0], s[1]);
}

// ---- per-(valid-pair, channel) SSIM + L1; unique-cell stores (r3/r7-measured-fast) ----
__global__ __launch_bounds__(256) void k_pair(const int* __restrict__ list,
                                              const int* __restrict__ count,
                                              const float* __restrict__ crops,
                                              const float* __restrict__ mus,
                                              const float* __restrict__ sigs,
                                              float* __restrict__ pairL1,
                                              float* __restrict__ pairSS) {
    const int c = blockIdx.x;      // 0..2
    const int n = *count;
    const int t = threadIdx.x;
    const int y = t >> 3;
    const int xb = (t & 7) * 4;
    const int wave = t >> 6, lane = t & 63;

    __shared__ float gp[SZ][PSTA];
    __shared__ float tmp[APR][PST];
    __shared__ float rl[4], rs[4];
    constexpr float GW[WIN] = GW_INIT;

    // zero conv aprons once; interior is rewritten each slot iteration
    for (int i = t; i < SZ * 10; i += 256) {
        int r = i / 10, cc = i % 10;
        gp[r][cc < 5 ? cc : cc + 32] = 0.f;
    }
    for (int i = t; i < 10 * PST; i += 256) {
        int r = i / PST, cc = i % PST;
        int rr = (r < 5) ? r : r + 32;
        tmp[rr][cc] = 0.f;
    }

    for (int slot = blockIdx.y; slot < n; slot += NSLOT) {
        const int pair = list[slot];
        const int b = pair >> 10;
        const int r = pair & 1023;
        const int gi = r >> 6, pi = r & 63;
        const size_t goff = (size_t)(b * NG + gi) * NPIX + c * CPIX;
        const size_t poff = (size_t)(BB * NG + b * NP + pi) * NPIX + c * CPIX;

        float4 gv = *(const float4*)(crops + goff + t * 4);
        float4 pv = *(const float4*)(crops + poff + t * 4);
        // hoist mu/sigma loads: in flight across both conv phases
        float4 mg = *(const float4*)(mus + goff + t * 4);
        float4 mp = *(const float4*)(mus + poff + t * 4);
        float4 sg = *(const float4*)(sigs + goff + t * 4);
        float4 sp = *(const float4*)(sigs + poff + t * 4);

        float l1 = fabsf(gv.x - pv.x) + fabsf(gv.y - pv.y) +
                   fabsf(gv.z - pv.z) + fabsf(gv.w - pv.w);
        gp[y][xb + 5] = gv.x * pv.x;
        gp[y][xb + 6] = gv.y * pv.y;
        gp[y][xb + 7] = gv.z * pv.z;
        gp[y][xb + 8] = gv.w * pv.w;
        __syncthreads();

#pragma unroll
        for (int j = 0; j < 4; ++j) {
            int x = xb + j;
            float a = 0.f;
#pragma unroll
            for (int k = 0; k < WIN; ++k) a += GW[k] * gp[y][x + k];
            tmp[y + 5][x] = a;
        }
        __syncthreads();

        float mgv[4] = {mg.x, mg.y, mg.z, mg.w};
        float mpv[4] = {mp.x, mp.y, mp.z, mp.w};
        float sgv[4] = {sg.x, sg.y, sg.z, sg.w};
        float spv[4] = {sp.x, sp.y, sp.z, sp.w};
        float ss = 0.f;
#pragma unroll
        for (int j = 0; j < 4; ++j) {
            int x = xb + j;
            float a = 0.f;
#pragma unroll
            for (int k = 0; k < WIN; ++k) a += GW[k] * tmp[y + k][x];
            float m1 = mgv[j], m2 = mpv[j];
            float sgp = a - m1 * m2;
            float num = (2.f * m1 * m2 + SSIM_C1) * (2.f * sgp + SSIM_C2);
            float den = (m1 * m1 + m2 * m2 + SSIM_C1) * (sgv[j] + spv[j] + SSIM_C2);
            ss += num / den;
        }

        // block reduction: 64-lane shuffle, then LDS across 4 waves
#pragma unroll
        for (int off = 32; off > 0; off >>= 1) {
            l1 += __shfl_down(l1, off);
            ss += __shfl_down(ss, off);
        }
        if (lane == 0) { rl[wave] = l1; rs[wave] = ss; }
        __syncthreads();
        if (t == 0) {
            pairL1[slot * 3 + c] = rl[0] + rl[1] + rl[2] + rl[3];
            pairSS[slot * 3 + c] = rs[0] + rs[1] + rs[2] + rs[3];
        }
    }
}

// ---- finalize: deterministic reduction over compact results ----
__global__ __launch_bounds__(256) void k_final(const int* __restrict__ count,
                                               const float* __restrict__ pairL1,
                                               const float* __restrict__ pairSS,
                                               float* __restrict__ out) {
    const int n3 = (*count) * 3;
    const int t = threadIdx.x;
    float L = 0.f, S = 0.f;
    for (int i = t; i < n3; i += 256) {
        L += pairL1[i];
        S += pairSS[i];
    }
    __shared__ float rl[4], rs[4];
#pragma unroll
    for (int off = 32; off > 0; off >>= 1) {
        L += __shfl_down(L, off);
        S += __shfl_down(S, off);
    }
    const int wave = t >> 6, lane = t & 63;
    if (lane == 0) { rl[wave] = L; rs[wave] = S; }
    __syncthreads();
    if (t == 0) {
        float cnt = (float)(*count);
        float Lt = (rl[0] + rl[1] + rl[2] + rl[3]) * (1.0f / (255.0f * (float)NPIX));
        float St = (rs[0] + rs[1] + rs[2] + rs[3]) * (1.0f / (float)NPIX);
        float m = fmaxf(cnt, 1.f);
        float loss = Lt / m + 1.f - St / m;
        out[0] = (cnt > 0.f) ? loss : 0.f;
    }
}

extern "C" void kernel_launch(void* const* d_in, const int* in_sizes, int n_in,
                              void* d_out, int out_size, void* d_ws, size_t ws_size,
                              hipStream_t stream) {
    const float* imgs = (const float*)d_in[0];  // (4,3,640,640)
    const float* gt = (const float*)d_in[1];    // (4,16,4)
    const float* pr = (const float*)d_in[2];    // (4,64,4)

    float* ws = (float*)d_ws;
    float* crops = ws;                                   // 320*3072
    float* mus = crops + (size_t)NCROP * NPIX;
    float* sigs = mus + (size_t)NCROP * NPIX;
    float* pairL1 = sigs + (size_t)NCROP * NPIX;         // 4096*3
    float* pairSS = pairL1 + (size_t)NPAIR * 3;          // 4096*3
    int* list = (int*)(pairSS + (size_t)NPAIR * 3);      // 4096
    int* count = list + NPAIR;                           // 1

    k_crop_valid<<<3 * NCROP + 1, 512, 0, stream>>>(imgs, gt, pr, crops, mus, sigs,
                                                    list, count);
    k_pair<<<dim3(3, NSLOT), 256, 0, stream>>>(list, count, crops, mus, sigs,
                                               pairL1, pairSS);
    k_final<<<1, 256, 0, stream>>>(count, pairL1, pairSS, (float*)d_out);
}